// Round 15
// baseline (150.739 us; speedup 1.0000x reference)
//
#include <hip/hip_runtime.h>

typedef unsigned short ushort;
typedef __attribute__((ext_vector_type(8))) short bf16x8;
typedef __attribute__((ext_vector_type(4))) float f32x4;
typedef __attribute__((ext_vector_type(4))) ushort us4;

#define NBATCH 32
#define ICN 256
#define OCN 256
#define HSZ 56
#define WSZ 56
#define HP 58
#define SPAT (HP*HP)            /* 3364 */
#define KTOT 2304               /* 9*256, k = (kh*3+kw)*256 + ic */
#define MTOT (NBATCH*HSZ*WSZ)   /* 100352 = 2^11 * 7^2 */
#define NT   (KTOT/64)          /* 36 K-tiles of BK=64 */
#define BM   224                /* grid 448 -> 87.5% capacity */

#define XP_BYTES ((size_t)NBATCH*SPAT*ICN*2)    /* 55,115,776 */
#define WD_BYTES ((size_t)OCN*KTOT*4)           /* 2,359,296  */

__device__ __forceinline__ ushort f2bf(float f) {
  union { float f; unsigned u; } c; c.f = f;
  unsigned r = c.u + 0x7FFFu + ((c.u >> 16) & 1u);
  return (ushort)(r >> 16);
}

// x [N][IC][56][56] f32 -> xp [N][58][58][IC] bf16, halo rows/cols written as 0.
__global__ void k_transpose(const float* __restrict__ x, ushort* __restrict__ xp) {
  __shared__ ushort t2[WSZ*264];
  int h = blockIdx.x, n = blockIdx.y;
  ushort* dst = xp + ((size_t)n*SPAT + (size_t)h*HP)*ICN;
  if (h == 0 || h == HP-1) {
    for (int e = threadIdx.x; e < HP*ICN/4; e += 256) ((us4*)dst)[e] = (us4){0,0,0,0};
    return;
  }
  const float* src = x + ((size_t)n*ICN*HSZ*WSZ) + (size_t)(h-1)*WSZ;
  for (int e = threadIdx.x; e < ICN*WSZ; e += 256) {
    int ic = e / WSZ, w = e - ic*WSZ;
    t2[w*264 + ic] = f2bf(src[(size_t)ic*(HSZ*WSZ) + w]);
  }
  __syncthreads();
  for (int e4 = threadIdx.x; e4 < HP*ICN/4; e4 += 256) {
    int wp = e4 >> 6, ic4 = (e4 & 63) << 2;
    us4 v = (wp == 0 || wp == HP-1) ? (us4){0,0,0,0}
                                    : *(const us4*)&t2[(wp-1)*264 + ic4];
    ((us4*)dst)[e4] = v;
  }
}

__global__ void k_scatter(const int* __restrict__ idx, const float* __restrict__ val,
                          float* __restrict__ wd, int nnz) {
  int i = blockIdx.x*256 + threadIdx.x;
  if (i >= nnz) return;
  int id = idx[i];
  int oc = id / (ICN*9);
  int rem = id - oc*(ICN*9);
  int ic = rem / 9;
  int k9 = rem - ic*9;
  atomicAdd(wd + (size_t)oc*KTOT + k9*ICN + ic, val[i]);
}

// B in 16x16x32 per-lane fragment order (R10-proven)
__global__ void k_convert3(const float* __restrict__ wd, ushort* __restrict__ bm3) {
  int e = blockIdx.x*256 + threadIdx.x;
  int lam = e & 63;
  int f   = (e >> 6) & 3;
  int wc  = (e >> 8) & 3;
  int kh  = (e >> 10) & 1;
  int t   = e >> 11;
  int oc  = wc*64 + f*16 + (lam & 15);
  int k   = (t >> 2)*256 + (t & 3)*64 + kh*32 + (lam >> 4)*8;
  const float* src = wd + (size_t)oc*KTOT + k;
  float4 v0 = *(const float4*)(src);
  float4 v1 = *(const float4*)(src + 4);
  us4 lo, hi;
  lo[0]=f2bf(v0.x); lo[1]=f2bf(v0.y); lo[2]=f2bf(v0.z); lo[3]=f2bf(v0.w);
  hi[0]=f2bf(v1.x); hi[1]=f2bf(v1.y); hi[2]=f2bf(v1.z); hi[3]=f2bf(v1.w);
  ushort* dst = bm3 + (size_t)e*8;
  *(us4*)(dst) = lo; *(us4*)(dst+4) = hi;
}

// --- 224x256 implicit-GEMM, R13 pipeline + PARITY-STAGGERED burst bodies ----
// Parity = wr = wv>>2 (SIMD-mates are {wv, wv+4} under wv%4 mapping).
// Even (wr=0): R13-verbatim bursts {reads, stage/GLB, waits, 16/12 MFMA}.
// Odd  (wr=1): split bursts {waits, 8 MFMA, mid-burst reads, 8 MFMA} so an
// odd wave's MFMA overlays its SIMD-mate's LDS/wait window and vice versa.
// GLB/STAGE/VMW per-burst membership IDENTICAL across parities -> same vmcnt
// FIFO proof as R13: enter t [stage(t+1)4, bvA4]; b0 +bvB, VMW(4); b1/b2
// +stage(t+2) 2+2; b2 VMW(4); b3 +bvA'.  Never vmcnt(0) in main loop.
// Odd ds FIFO: b0 LGKM(0) [avq0+avq1=7 drain]; b2 LGKM(3) [avq2(4)+avq3(3)
// -> drain avq2]; b3 LGKM(4) [avq3(3)+avq0'(4) -> drain avq3].  qed.

#define GLD(gsrc, ldst) __builtin_amdgcn_global_load_lds( \
    (const __attribute__((address_space(1))) void*)(gsrc), \
    (__attribute__((address_space(3))) void*)(ldst), 16, 0, 0)
#define BAR()  asm volatile("s_barrier" ::: "memory")
#define VMW(N) do { asm volatile("s_waitcnt vmcnt(" #N ")" ::: "memory"); \
                    __builtin_amdgcn_sched_barrier(0); } while (0)
#define LGKM(N) do { asm volatile("s_waitcnt lgkmcnt(" #N ")" ::: "memory"); \
                     __builtin_amdgcn_sched_barrier(0); } while (0)
#define SB() __builtin_amdgcn_sched_barrier(0)

#define BUF_US  14848
#define BUF_B   29696

#define STAGE2X(T2, PAIR, BUFUS) do { \
    const int t4_ = (T2) >> 2; const int khh_ = t4_/3, khw_ = t4_ - khh_*3; \
    const int koff_ = (khh_*HP + khw_)*256 + (((T2) & 3) << 6); \
    ushort* b_ = Ab + (BUFUS); \
    GLD(xp + ((PAIR) ? sA2 : sA0) + koff_, b_ + ((PAIR) ? dO2 : dO0)); \
    GLD(xp + ((PAIR) ? sA3 : sA1) + koff_, b_ + ((PAIR) ? dO3 : dO1)); } while (0)

#define GLB(DST, VOFF) \
    asm volatile("global_load_dwordx4 %0, %4, %5 offset:0\n\t" \
                 "global_load_dwordx4 %1, %4, %5 offset:1024\n\t" \
                 "global_load_dwordx4 %2, %4, %5 offset:2048\n\t" \
                 "global_load_dwordx4 %3, %4, %5 offset:3072" \
                 : "=&v"(DST[0]), "=&v"(DST[1]), "=&v"(DST[2]), "=&v"(DST[3]) \
                 : "v"(VOFF), "s"(bm3) : "memory")

#define LOADA4(DST, KH, BFB) do { \
    unsigned a_ = ((KH) ? aL1v : aL0v) + (unsigned)(BFB); \
    asm volatile("ds_read_b128 %0, %4 offset:0\n\t" \
                 "ds_read_b128 %1, %4 offset:2048\n\t" \
                 "ds_read_b128 %2, %4 offset:4096\n\t" \
                 "ds_read_b128 %3, %4 offset:6144" \
                 : "=&v"(DST[0]), "=&v"(DST[1]), "=&v"(DST[2]), "=&v"(DST[3]) \
                 : "v"(a_)); } while (0)

#define LOADA3(DST, KH, BFB) do { \
    unsigned a_ = ((KH) ? aL1v : aL0v) + (unsigned)((BFB) + 8192); \
    asm volatile("ds_read_b128 %0, %3 offset:0\n\t" \
                 "ds_read_b128 %1, %3 offset:2048\n\t" \
                 "ds_read_b128 %2, %3 offset:4096" \
                 : "=&v"(DST[0]), "=&v"(DST[1]), "=&v"(DST[2]) \
                 : "v"(a_)); } while (0)

#define MFMA16(AV, BV) do { \
    __builtin_amdgcn_s_setprio(1); \
    _Pragma("unroll") \
    for (int f_ = 0; f_ < 4; ++f_) { \
      _Pragma("unroll") \
      for (int n_ = 0; n_ < 4; ++n_) \
        acc[f_][n_] = __builtin_amdgcn_mfma_f32_16x16x32_bf16( \
            AV[f_], BV[n_], acc[f_][n_], 0, 0, 0); \
    } \
    __builtin_amdgcn_s_setprio(0); } while (0)

#define MFMA12(AV, BV) do { \
    __builtin_amdgcn_s_setprio(1); \
    _Pragma("unroll") \
    for (int f_ = 0; f_ < 3; ++f_) { \
      _Pragma("unroll") \
      for (int n_ = 0; n_ < 4; ++n_) \
        acc[4+f_][n_] = __builtin_amdgcn_mfma_f32_16x16x32_bf16( \
            AV[f_], BV[n_], acc[4+f_][n_], 0, 0, 0); \
    } \
    __builtin_amdgcn_s_setprio(0); } while (0)

// half-bursts for odd parity
#define MFMA8_01(AV, BV) do { \
    __builtin_amdgcn_s_setprio(1); \
    _Pragma("unroll") \
    for (int f_ = 0; f_ < 2; ++f_) { \
      _Pragma("unroll") \
      for (int n_ = 0; n_ < 4; ++n_) \
        acc[f_][n_] = __builtin_amdgcn_mfma_f32_16x16x32_bf16( \
            AV[f_], BV[n_], acc[f_][n_], 0, 0, 0); \
    } \
    __builtin_amdgcn_s_setprio(0); } while (0)

#define MFMA8_23(AV, BV) do { \
    __builtin_amdgcn_s_setprio(1); \
    _Pragma("unroll") \
    for (int f_ = 2; f_ < 4; ++f_) { \
      _Pragma("unroll") \
      for (int n_ = 0; n_ < 4; ++n_) \
        acc[f_][n_] = __builtin_amdgcn_mfma_f32_16x16x32_bf16( \
            AV[f_], BV[n_], acc[f_][n_], 0, 0, 0); \
    } \
    __builtin_amdgcn_s_setprio(0); } while (0)

#define MFMA4_0(AV, BV) do { \
    __builtin_amdgcn_s_setprio(1); \
    _Pragma("unroll") \
    for (int n_ = 0; n_ < 4; ++n_) \
      acc[4][n_] = __builtin_amdgcn_mfma_f32_16x16x32_bf16( \
          AV[0], BV[n_], acc[4][n_], 0, 0, 0); \
    __builtin_amdgcn_s_setprio(0); } while (0)

#define MFMA8_12(AV, BV) do { \
    __builtin_amdgcn_s_setprio(1); \
    _Pragma("unroll") \
    for (int f_ = 1; f_ < 3; ++f_) { \
      _Pragma("unroll") \
      for (int n_ = 0; n_ < 4; ++n_) \
        acc[4+f_][n_] = __builtin_amdgcn_mfma_f32_16x16x32_bf16( \
            AV[f_], BV[n_], acc[4+f_][n_], 0, 0, 0); \
    } \
    __builtin_amdgcn_s_setprio(0); } while (0)

__global__ __launch_bounds__(512, 2) void k_gemm8(const ushort* __restrict__ xp,
                                                  const ushort* __restrict__ bm3,
                                                  const float* __restrict__ bias,
                                                  float* __restrict__ out) {
  __shared__ __align__(128) ushort Ab[3*BUF_US];   // 87 KB

  const int tid = threadIdx.x;
  const int lam = tid & 63;
  const int wv  = tid >> 6;            // 0..7
  const int wr  = wv >> 2;             // 0..1 (M half = u; ALSO stagger parity)
  const int wc  = wv & 3;              // 0..3  (N quarter)
  const int la  = lam & 15;
  const int m0  = blockIdx.x * BM;

  const unsigned AbB = (unsigned)(uintptr_t)(__attribute__((address_space(3))) char*)Ab;

  const int q0 = (lam >> 4) ^ (la & 7);
  const unsigned aL0v = AbB + wr*14336 + la*128 + q0*16;
  const unsigned aL1v = AbB + wr*14336 + la*128 + (q0 ^ 4)*16;
  const unsigned wcB = wc*4096 + lam*16;

  // staging: waves 0-6 real, wave 7 dummies into dump slot (R13-proven)
  int sA0, sA1, sA2, sA3;
  int dO0, dO1, dO2, dO3;
  if (wv < 7) {
    const int oA = (lam & 7) ^ (lam >> 3);
    int m, n, rem, oh, ow, r;
    r = (wv*4 + 0)*8 + (lam >> 3);
    m = m0 + r; n = m/3136; rem = m - n*3136; oh = rem/56; ow = rem - oh*56;
    sA0 = (n*SPAT + oh*HP + ow)*ICN + oA*8;  dO0 = (wv*4 + 0)*512;
    r = (wv*4 + 1)*8 + (lam >> 3);
    m = m0 + r; n = m/3136; rem = m - n*3136; oh = rem/56; ow = rem - oh*56;
    sA1 = (n*SPAT + oh*HP + ow)*ICN + oA*8;  dO1 = (wv*4 + 1)*512;
    r = (wv*4 + 2)*8 + (lam >> 3);
    m = m0 + r; n = m/3136; rem = m - n*3136; oh = rem/56; ow = rem - oh*56;
    sA2 = (n*SPAT + oh*HP + ow)*ICN + oA*8;  dO2 = (wv*4 + 2)*512;
    r = (wv*4 + 3)*8 + (lam >> 3);
    m = m0 + r; n = m/3136; rem = m - n*3136; oh = rem/56; ow = rem - oh*56;
    sA3 = (n*SPAT + oh*HP + ow)*ICN + oA*8;  dO3 = (wv*4 + 3)*512;
  } else {
    sA0 = sA1 = sA2 = sA3 = 0;
    dO0 = dO1 = dO2 = dO3 = 14336;
  }

  f32x4 acc[7][4];
#pragma unroll
  for (int a = 0; a < 7; ++a)
#pragma unroll
    for (int b = 0; b < 4; ++b) acc[a][b] = (f32x4){0.f, 0.f, 0.f, 0.f};

  bf16x8 avq0_[4], avq1_[3], avq2_[4], avq3_[3], bvA_[4], bvB_[4];

  // prologue
  STAGE2X(0, 0, 0);       STAGE2X(0, 1, 0);
  STAGE2X(1, 0, BUF_US);  STAGE2X(1, 1, BUF_US);
  GLB(bvA_, wcB);
  VMW(4);
  BAR();
  LOADA4(avq0_, 0, 0); LOADA3(avq1_, 0, 0);

  int bf0b = 0, bf1b = BUF_B, bf2b = 2*BUF_B;
  int bf2u = 2*BUF_US;
  if (wr == 0) {
    // ---------------- even parity: R13-verbatim main loop ----------------
    for (int t = 0; t < NT-2; ++t) {
      const unsigned vb = (unsigned)t*32768 + wcB;
      LOADA4(avq2_, 1, bf0b);
      GLB(bvB_, vb + 16384);
      VMW(4);
      LGKM(7);
      MFMA16(avq0_, bvA_);
      LOADA3(avq3_, 1, bf0b);
      STAGE2X(t+2, 0, bf2u);
      LGKM(7);
      MFMA12(avq1_, bvA_);
      BAR();
      LOADA4(avq0_, 0, bf1b);
      STAGE2X(t+2, 1, bf2u);
      VMW(4);
      LGKM(7);
      MFMA16(avq2_, bvB_);
      LOADA3(avq1_, 0, bf1b);
      GLB(bvA_, vb + 32768);
      LGKM(7);
      MFMA12(avq3_, bvB_);
      BAR();
      int bt = bf0b; bf0b = bf1b; bf1b = bf2b; bf2b = bt;
      bf2u = bf2b / 2;
    }
  } else {
    // -------- odd parity: split-MFMA bursts (stagger vs SIMD-mate) --------
    for (int t = 0; t < NT-2; ++t) {
      const unsigned vb = (unsigned)t*32768 + wcB;
      // b0
      GLB(bvB_, vb + 16384);
      VMW(4);
      LGKM(0);                   // avq0(4)+avq1(3) drained
      MFMA8_01(avq0_, bvA_);
      SB();
      LOADA4(avq2_, 1, bf0b);
      SB();
      MFMA8_23(avq0_, bvA_);
      // b1
      STAGE2X(t+2, 0, bf2u);
      MFMA4_0(avq1_, bvA_);
      SB();
      LOADA3(avq3_, 1, bf0b);
      SB();
      MFMA8_12(avq1_, bvA_);
      BAR();
      // b2
      STAGE2X(t+2, 1, bf2u);
      VMW(4);
      LGKM(3);                   // avq2 drained (avq3 in flight)
      MFMA8_01(avq2_, bvB_);
      SB();
      LOADA4(avq0_, 0, bf1b);
      SB();
      MFMA8_23(avq2_, bvB_);
      // b3
      GLB(bvA_, vb + 32768);
      LGKM(4);                   // avq3 drained (avq0' in flight)
      MFMA4_0(avq3_, bvB_);
      SB();
      LOADA3(avq1_, 0, bf1b);
      SB();
      MFMA8_12(avq3_, bvB_);
      BAR();
      int bt = bf0b; bf0b = bf1b; bf1b = bf2b; bf2b = bt;
      bf2u = bf2b / 2;
    }
  }

  // peel t = NT-2 (parity-agnostic; both parities enter with avq0+avq1=7 in flight)
  {
    const unsigned vb = (unsigned)(NT-2)*32768 + wcB;
    LOADA4(avq2_, 1, bf0b);
    GLB(bvB_, vb + 16384);
    VMW(4);
    LGKM(7);
    MFMA16(avq0_, bvA_);
    LOADA3(avq3_, 1, bf0b);
    LGKM(7);
    MFMA12(avq1_, bvA_);
    BAR();
    LOADA4(avq0_, 0, bf1b);
    VMW(0);
    LGKM(7);
    MFMA16(avq2_, bvB_);
    LOADA3(avq1_, 0, bf1b);
    GLB(bvA_, vb + 32768);
    LGKM(7);
    MFMA12(avq3_, bvB_);
    BAR();
    int bt = bf0b; bf0b = bf1b; bf1b = bf2b; bf2b = bt;
  }

  // peel t = NT-1
  {
    const unsigned vb = (unsigned)(NT-1)*32768 + wcB;
    LOADA4(avq2_, 1, bf0b);
    GLB(bvB_, vb + 16384);
    VMW(4);
    LGKM(7);
    MFMA16(avq0_, bvA_);
    LOADA3(avq3_, 1, bf0b);
    LGKM(7);
    MFMA12(avq1_, bvA_);
    VMW(0);
    LGKM(3);
    MFMA16(avq2_, bvB_);
    LGKM(0);
    MFMA12(avq3_, bvB_);
  }

  // epilogue
#pragma unroll
  for (int nn = 0; nn < 4; ++nn) {
    int oc = wc*64 + nn*16 + la;
    float bvs = bias[oc];
#pragma unroll
    for (int mf = 0; mf < 7; ++mf) {
      int m = m0 + wr*112 + mf*16 + ((lam >> 4) << 2);
      int n = m / 3136;
      int rem = m - n*3136;
      float4 o;
      o.x = acc[mf][nn][0] + bvs;
      o.y = acc[mf][nn][1] + bvs;
      o.z = acc[mf][nn][2] + bvs;
      o.w = acc[mf][nn][3] + bvs;
      *(float4*)(out + ((size_t)(n*OCN + oc))*3136 + rem) = o;
    }
  }
}

extern "C" void kernel_launch(void* const* d_in, const int* in_sizes, int n_in,
                              void* d_out, int out_size, void* d_ws, size_t ws_size,
                              hipStream_t stream) {
  const float* x    = (const float*)d_in[0];
  const float* wval = (const float*)d_in[1];
  const int*   widx = (const int*)d_in[2];
  const float* bias = (const float*)d_in[3];
  float* out = (float*)d_out;
  const int nnz = in_sizes[1];

  char* ws = (char*)d_ws;
  ushort* xp  = (ushort*)ws;                              // 55.1 MB
  float*  wd  = (float*)(ws + XP_BYTES);                  // 2.36 MB
  ushort* bm3 = (ushort*)(ws + XP_BYTES + WD_BYTES);      // 1.125 MB

  hipMemsetAsync(wd, 0, WD_BYTES, stream);
  k_transpose<<<dim3(HP, NBATCH), 256, 0, stream>>>(x, xp);
  k_scatter<<<dim3((nnz + 255)/256), 256, 0, stream>>>(widx, wval, wd, nnz);
  k_convert3<<<dim3((NT*2*16*64)/256), 256, 0, stream>>>(wd, bm3);
  k_gemm8<<<dim3(MTOT/BM), 512, 0, stream>>>(xp, bm3, bias, out);
}

// Round 17
// 148.936 us; speedup vs baseline: 1.0121x; 1.0121x over previous
//
#include <hip/hip_runtime.h>

typedef unsigned short ushort;
typedef __attribute__((ext_vector_type(8))) short bf16x8;
typedef __attribute__((ext_vector_type(4))) float f32x4;
typedef __attribute__((ext_vector_type(4))) ushort us4;

#define NBATCH 32
#define ICN 256
#define OCN 256
#define HSZ 56
#define WSZ 56
#define HP 58
#define SPAT (HP*HP)            /* 3364 */
#define KTOT 2304               /* 9*256, k = (kh*3+kw)*256 + ic */
#define MTOT (NBATCH*HSZ*WSZ)   /* 100352 = 2^11 * 7^2 */
#define NT   (KTOT/64)          /* 36 K-tiles of BK=64 */
#define BM   224                /* divides MTOT exactly: grid 448 -> 87.5% cap */

#define XP_BYTES ((size_t)NBATCH*SPAT*ICN*2)    /* 55,115,776 */
#define WD_BYTES ((size_t)OCN*KTOT*4)           /* 2,359,296  */

__device__ __forceinline__ ushort f2bf(float f) {
  union { float f; unsigned u; } c; c.f = f;
  unsigned r = c.u + 0x7FFFu + ((c.u >> 16) & 1u);
  return (ushort)(r >> 16);
}

// x [N][IC][56][56] f32 -> xp [N][58][58][IC] bf16, halo rows/cols written as 0.
__global__ void k_transpose(const float* __restrict__ x, ushort* __restrict__ xp) {
  __shared__ ushort t2[WSZ*264];
  int h = blockIdx.x, n = blockIdx.y;          // h = padded row 0..57
  ushort* dst = xp + ((size_t)n*SPAT + (size_t)h*HP)*ICN;
  if (h == 0 || h == HP-1) {
    for (int e = threadIdx.x; e < HP*ICN/4; e += 256) ((us4*)dst)[e] = (us4){0,0,0,0};
    return;
  }
  const float* src = x + ((size_t)n*ICN*HSZ*WSZ) + (size_t)(h-1)*WSZ;
  for (int e = threadIdx.x; e < ICN*WSZ; e += 256) {
    int ic = e / WSZ, w = e - ic*WSZ;
    t2[w*264 + ic] = f2bf(src[(size_t)ic*(HSZ*WSZ) + w]);
  }
  __syncthreads();
  for (int e4 = threadIdx.x; e4 < HP*ICN/4; e4 += 256) {
    int wp = e4 >> 6, ic4 = (e4 & 63) << 2;
    us4 v = (wp == 0 || wp == HP-1) ? (us4){0,0,0,0}
                                    : *(const us4*)&t2[(wp-1)*264 + ic4];
    ((us4*)dst)[e4] = v;
  }
}

// COO scatter into dense fp32 W [oc][k], duplicates sum via atomicAdd
__global__ void k_scatter(const int* __restrict__ idx, const float* __restrict__ val,
                          float* __restrict__ wd, int nnz) {
  int i = blockIdx.x*256 + threadIdx.x;
  if (i >= nnz) return;
  int id = idx[i];
  int oc = id / (ICN*9);
  int rem = id - oc*(ICN*9);
  int ic = rem / 9;
  int k9 = rem - ic*9;
  atomicAdd(wd + (size_t)oc*KTOT + k9*ICN + ic, val[i]);
}

// B in 16x16x32 per-lane fragment order (R10-proven):
// 16B unit u = ((t*2+kh)*16 + wc*4 + f)*64 + lam holds
//   wd[oc = wc*64 + f*16 + (lam&15)][k = (t>>2)*256 + (t&3)*64 + kh*32 + (lam>>4)*8 ..+8]
__global__ void k_convert3(const float* __restrict__ wd, ushort* __restrict__ bm3) {
  int e = blockIdx.x*256 + threadIdx.x;
  int lam = e & 63;
  int f   = (e >> 6) & 3;
  int wc  = (e >> 8) & 3;
  int kh  = (e >> 10) & 1;
  int t   = e >> 11;
  int oc  = wc*64 + f*16 + (lam & 15);
  int k   = (t >> 2)*256 + (t & 3)*64 + kh*32 + (lam >> 4)*8;
  const float* src = wd + (size_t)oc*KTOT + k;
  float4 v0 = *(const float4*)(src);
  float4 v1 = *(const float4*)(src + 4);
  us4 lo, hi;
  lo[0]=f2bf(v0.x); lo[1]=f2bf(v0.y); lo[2]=f2bf(v0.z); lo[3]=f2bf(v0.w);
  hi[0]=f2bf(v1.x); hi[1]=f2bf(v1.y); hi[2]=f2bf(v1.z); hi[3]=f2bf(v1.w);
  ushort* dst = bm3 + (size_t)e*8;
  *(us4*)(dst) = lo; *(us4*)(dst+4) = hi;
}

// --- 224x256 implicit-GEMM (R13: verified best, 116 µs / MfmaUtil 42%) -----
// A LDS: 3 buffers x [u 2 x 112 rows x 64 k (XOR-swz oct) + 512-ushort dump].
// Buffer = 14848 ushorts (29696 B); total 87 KB -> 1 block/CU.
// Staging: 28 real gld_lds/tile by waves 0-6 (4 each); wave 7 issues 4 DUMMY
// loads into the target buffer's dump slot so every wave's vmcnt FIFO is
// identical.  vmcnt: enter t [stage(t+1)4, bvA4]; b0 +bvB, VMW(4); b1/b2
// +stage(t+2) 2+2; b2 VMW(4); b3 +bvA(t+1).  Never vmcnt(0) in main loop.
// ds FIFO: bursts read 4/3/4/3 (mh0=4 frags, mh1=3); uniform LGKM(7).
// Bursts: (kh0,mh0)=16 MFMA, (kh0,mh1)=12, (kh1,mh0)=16, (kh1,mh1)=12.

#define GLD(gsrc, ldst) __builtin_amdgcn_global_load_lds( \
    (const __attribute__((address_space(1))) void*)(gsrc), \
    (__attribute__((address_space(3))) void*)(ldst), 16, 0, 0)
#define BAR()  asm volatile("s_barrier" ::: "memory")
#define VMW(N) do { asm volatile("s_waitcnt vmcnt(" #N ")" ::: "memory"); \
                    __builtin_amdgcn_sched_barrier(0); } while (0)
#define LGKM(N) do { asm volatile("s_waitcnt lgkmcnt(" #N ")" ::: "memory"); \
                     __builtin_amdgcn_sched_barrier(0); } while (0)

#define BUF_US  14848          /* ushorts per buffer (incl. dump) */
#define BUF_B   29696          /* bytes per buffer */

#define STAGE2X(T2, PAIR, BUFUS) do { \
    const int t4_ = (T2) >> 2; const int khh_ = t4_/3, khw_ = t4_ - khh_*3; \
    const int koff_ = (khh_*HP + khw_)*256 + (((T2) & 3) << 6); \
    ushort* b_ = Ab + (BUFUS); \
    GLD(xp + ((PAIR) ? sA2 : sA0) + koff_, b_ + ((PAIR) ? dO2 : dO0)); \
    GLD(xp + ((PAIR) ? sA3 : sA1) + koff_, b_ + ((PAIR) ? dO3 : dO1)); } while (0)

#define GLB(DST, VOFF) \
    asm volatile("global_load_dwordx4 %0, %4, %5 offset:0\n\t" \
                 "global_load_dwordx4 %1, %4, %5 offset:1024\n\t" \
                 "global_load_dwordx4 %2, %4, %5 offset:2048\n\t" \
                 "global_load_dwordx4 %3, %4, %5 offset:3072" \
                 : "=&v"(DST[0]), "=&v"(DST[1]), "=&v"(DST[2]), "=&v"(DST[3]) \
                 : "v"(VOFF), "s"(bm3) : "memory")

#define LOADA4(DST, KH, BFB) do { \
    unsigned a_ = ((KH) ? aL1v : aL0v) + (unsigned)(BFB); \
    asm volatile("ds_read_b128 %0, %4 offset:0\n\t" \
                 "ds_read_b128 %1, %4 offset:2048\n\t" \
                 "ds_read_b128 %2, %4 offset:4096\n\t" \
                 "ds_read_b128 %3, %4 offset:6144" \
                 : "=&v"(DST[0]), "=&v"(DST[1]), "=&v"(DST[2]), "=&v"(DST[3]) \
                 : "v"(a_)); } while (0)

#define LOADA3(DST, KH, BFB) do { \
    unsigned a_ = ((KH) ? aL1v : aL0v) + (unsigned)((BFB) + 8192); \
    asm volatile("ds_read_b128 %0, %3 offset:0\n\t" \
                 "ds_read_b128 %1, %3 offset:2048\n\t" \
                 "ds_read_b128 %2, %3 offset:4096" \
                 : "=&v"(DST[0]), "=&v"(DST[1]), "=&v"(DST[2]) \
                 : "v"(a_)); } while (0)

#define MFMA16(AV, BV) do { \
    __builtin_amdgcn_s_setprio(1); \
    _Pragma("unroll") \
    for (int f_ = 0; f_ < 4; ++f_) { \
      _Pragma("unroll") \
      for (int n_ = 0; n_ < 4; ++n_) \
        acc[f_][n_] = __builtin_amdgcn_mfma_f32_16x16x32_bf16( \
            AV[f_], BV[n_], acc[f_][n_], 0, 0, 0); \
    } \
    __builtin_amdgcn_s_setprio(0); } while (0)

#define MFMA12(AV, BV) do { \
    __builtin_amdgcn_s_setprio(1); \
    _Pragma("unroll") \
    for (int f_ = 0; f_ < 3; ++f_) { \
      _Pragma("unroll") \
      for (int n_ = 0; n_ < 4; ++n_) \
        acc[4+f_][n_] = __builtin_amdgcn_mfma_f32_16x16x32_bf16( \
            AV[f_], BV[n_], acc[4+f_][n_], 0, 0, 0); \
    } \
    __builtin_amdgcn_s_setprio(0); } while (0)

__global__ __launch_bounds__(512, 2) void k_gemm8(const ushort* __restrict__ xp,
                                                  const ushort* __restrict__ bm3,
                                                  const float* __restrict__ bias,
                                                  float* __restrict__ out) {
  __shared__ __align__(128) ushort Ab[3*BUF_US];   // 87 KB

  const int tid = threadIdx.x;
  const int lam = tid & 63;
  const int wv  = tid >> 6;            // 0..7
  const int wr  = wv >> 2;             // 0..1  (M half = A unit u, 112 rows)
  const int wc  = wv & 3;              // 0..3  (N quarter)
  const int la  = lam & 15;
  const int m0  = blockIdx.x * BM;

  const unsigned AbB = (unsigned)(uintptr_t)(__attribute__((address_space(3))) char*)Ab;

  // A read bases: byte = buf + u(wr)*14336 + mh*8192(at use) + r*128 + p*16,
  // r = f*16+la, p = (kh*4 + oq) ^ (la&7), oq = lam>>4.
  const int q0 = (lam >> 4) ^ (la & 7);
  const unsigned aL0v = AbB + wr*14336 + la*128 + q0*16;
  const unsigned aL1v = AbB + wr*14336 + la*128 + (q0 ^ 4)*16;

  // B voffset base (bm3, 16x16 frag order): + t*32768 + kh*16384 at use
  const unsigned wcB = wc*4096 + lam*16;

  // staging: waves 0-6 real (instr j = wv*4+i, rows 8j..8j+7, j=0..27);
  // wave 7: 4 dummies into this buffer's dump slot (ushort 14336).
  // logical oct o = (lam&7) ^ (lam>>3)  (phys = lam&7, r&7 = lam>>3).
  int sA0, sA1, sA2, sA3;
  int dO0, dO1, dO2, dO3;
  if (wv < 7) {
    const int oA = (lam & 7) ^ (lam >> 3);
    int m, n, rem, oh, ow, r;
    r = (wv*4 + 0)*8 + (lam >> 3);
    m = m0 + r; n = m/3136; rem = m - n*3136; oh = rem/56; ow = rem - oh*56;
    sA0 = (n*SPAT + oh*HP + ow)*ICN + oA*8;  dO0 = (wv*4 + 0)*512;
    r = (wv*4 + 1)*8 + (lam >> 3);
    m = m0 + r; n = m/3136; rem = m - n*3136; oh = rem/56; ow = rem - oh*56;
    sA1 = (n*SPAT + oh*HP + ow)*ICN + oA*8;  dO1 = (wv*4 + 1)*512;
    r = (wv*4 + 2)*8 + (lam >> 3);
    m = m0 + r; n = m/3136; rem = m - n*3136; oh = rem/56; ow = rem - oh*56;
    sA2 = (n*SPAT + oh*HP + ow)*ICN + oA*8;  dO2 = (wv*4 + 2)*512;
    r = (wv*4 + 3)*8 + (lam >> 3);
    m = m0 + r; n = m/3136; rem = m - n*3136; oh = rem/56; ow = rem - oh*56;
    sA3 = (n*SPAT + oh*HP + ow)*ICN + oA*8;  dO3 = (wv*4 + 3)*512;
  } else {
    sA0 = sA1 = sA2 = sA3 = 0;               // xp + koff: always valid
    dO0 = dO1 = dO2 = dO3 = 14336;           // dump slot (per buffer)
  }

  f32x4 acc[7][4];
#pragma unroll
  for (int a = 0; a < 7; ++a)
#pragma unroll
    for (int b = 0; b < 4; ++b) acc[a][b] = (f32x4){0.f, 0.f, 0.f, 0.f};

  // static register names (rule #20)
  bf16x8 avq0_[4], avq1_[3], avq2_[4], avq3_[3], bvA_[4], bvB_[4];

  // prologue: stage A(0)->buf0, A(1)->buf1; B(0,kh0).
  // VMW(4): drains 8 oldest (= both stage sets); bvA may remain in flight.
  STAGE2X(0, 0, 0);       STAGE2X(0, 1, 0);
  STAGE2X(1, 0, BUF_US);  STAGE2X(1, 1, BUF_US);
  GLB(bvA_, wcB);
  VMW(4);
  BAR();
  LOADA4(avq0_, 0, 0); LOADA3(avq1_, 0, 0);

  int bf0b = 0, bf1b = BUF_B, bf2b = 2*BUF_B;          // READ byte offsets
  int bf2u = 2*BUF_US;                                  // STAGE ushort offset
  for (int t = 0; t < NT-2; ++t) {
    const unsigned vb = (unsigned)t*32768 + wcB;
    // b0 (kh0,mh0): +bvB; read (kh1,mh0)
    LOADA4(avq2_, 1, bf0b);
    GLB(bvB_, vb + 16384);
    VMW(4);                    // bvA + stage(t+1) landed
    LGKM(7);                   // avq0 ready
    MFMA16(avq0_, bvA_);
    // b1 (kh0,mh1): read (kh1,mh1); stage(t+2) slots 0,1
    LOADA3(avq3_, 1, bf0b);
    STAGE2X(t+2, 0, bf2u);
    LGKM(7);                   // avq1 ready
    MFMA12(avq1_, bvA_);
    BAR();                     // MID: bf1 (tile t+1) block-wide visible
    // b2 (kh1,mh0): read (kh0,mh0) of t+1 from bf1; stage(t+2) slots 2,3
    LOADA4(avq0_, 0, bf1b);
    STAGE2X(t+2, 1, bf2u);
    VMW(4);                    // bvB landed; stage(t+2) outstanding
    LGKM(7);                   // avq2 ready
    MFMA16(avq2_, bvB_);
    // b3 (kh1,mh1): read (kh0,mh1) of t+1; +bvA(t+1)
    LOADA3(avq1_, 0, bf1b);
    GLB(bvA_, vb + 32768);
    LGKM(7);                   // avq3 ready (all bf0 reads drained)
    MFMA12(avq3_, bvB_);
    BAR();                     // END: bf0 safe to restage next tile
    int bt = bf0b; bf0b = bf1b; bf1b = bf2b; bf2b = bt;
    bf2u = bf2b / 2;
  }

  // peel t = NT-2: no staging (t+2 out of range)
  {
    const unsigned vb = (unsigned)(NT-2)*32768 + wcB;
    LOADA4(avq2_, 1, bf0b);
    GLB(bvB_, vb + 16384);
    VMW(4);                    // bvA + stage(NT-1) landed
    LGKM(7);
    MFMA16(avq0_, bvA_);
    LOADA3(avq3_, 1, bf0b);
    LGKM(7);
    MFMA12(avq1_, bvA_);
    BAR();                     // MID
    LOADA4(avq0_, 0, bf1b);
    VMW(0);                    // bvB landed (tail drain ok)
    LGKM(7);
    MFMA16(avq2_, bvB_);
    LOADA3(avq1_, 0, bf1b);
    GLB(bvA_, vb + 32768);
    LGKM(7);
    MFMA12(avq3_, bvB_);
    BAR();                     // END
    int bt = bf0b; bf0b = bf1b; bf1b = bf2b; bf2b = bt;
  }

  // peel t = NT-1: no staging, no next-tile reads
  {
    const unsigned vb = (unsigned)(NT-1)*32768 + wcB;
    LOADA4(avq2_, 1, bf0b);
    GLB(bvB_, vb + 16384);
    VMW(4);                    // bvA ready
    LGKM(7);
    MFMA16(avq0_, bvA_);
    LOADA3(avq3_, 1, bf0b);
    LGKM(7);
    MFMA12(avq1_, bvA_);
    VMW(0);                    // bvB ready
    LGKM(3);                   // avq2 ready (avq3 still in flight)
    MFMA16(avq2_, bvB_);
    LGKM(0);                   // avq3 ready
    MFMA12(avq3_, bvB_);
  }

  // epilogue: lane l -> col(oc) = la, rows m = base + (l>>4)*4 + j
#pragma unroll
  for (int nn = 0; nn < 4; ++nn) {
    int oc = wc*64 + nn*16 + la;
    float bvs = bias[oc];
#pragma unroll
    for (int mf = 0; mf < 7; ++mf) {
      int m = m0 + wr*112 + mf*16 + ((lam >> 4) << 2);
      int n = m / 3136;
      int rem = m - n*3136;     // float4 never straddles n (m aligned to 4)
      float4 o;
      o.x = acc[mf][nn][0] + bvs;
      o.y = acc[mf][nn][1] + bvs;
      o.z = acc[mf][nn][2] + bvs;
      o.w = acc[mf][nn][3] + bvs;
      *(float4*)(out + ((size_t)(n*OCN + oc))*3136 + rem) = o;
    }
  }
}

extern "C" void kernel_launch(void* const* d_in, const int* in_sizes, int n_in,
                              void* d_out, int out_size, void* d_ws, size_t ws_size,
                              hipStream_t stream) {
  const float* x    = (const float*)d_in[0];
  const float* wval = (const float*)d_in[1];
  const int*   widx = (const int*)d_in[2];
  const float* bias = (const float*)d_in[3];
  float* out = (float*)d_out;
  const int nnz = in_sizes[1];

  char* ws = (char*)d_ws;
  ushort* xp  = (ushort*)ws;                              // 55.1 MB
  float*  wd  = (float*)(ws + XP_BYTES);                  // 2.36 MB
  ushort* bm3 = (ushort*)(ws + XP_BYTES + WD_BYTES);      // 1.125 MB (frag-order B)

  hipMemsetAsync(wd, 0, WD_BYTES, stream);
  k_transpose<<<dim3(HP, NBATCH), 256, 0, stream>>>(x, xp);
  k_scatter<<<dim3((nnz + 255)/256), 256, 0, stream>>>(widx, wval, wd, nnz);
  k_convert3<<<dim3((NT*2*16*64)/256), 256, 0, stream>>>(wd, bm3);
  k_gemm8<<<dim3(MTOT/BM), 512, 0, stream>>>(xp, bm3, bias, out);
}